// Round 2
// baseline (178.985 us; speedup 1.0000x reference)
//
#include <hip/hip_runtime.h>
#include <math.h>

// ---------------------------------------------------------------------------
// QConv2dMedium: quantum conv = per-pixel 16-ch map
//   out[k] = clip(8 * |U[k,0:9] . p|^2 / max(||p||,1e-12)^2, 0, 1)
// U = (CNOT perms L1)(Layer1)(CNOT perms L0)(Layer0), 16x16 complex.
//
// R2: 4 pixels/thread to amortize the 288 coefficient broadcasts 4x,
// sliding window in registers, float4 stores. Memory-bound target ~23 us.
// ---------------------------------------------------------------------------

#define WIRES 4
#define DIM 16

__device__ inline void rot_entry(float phi, float th, float om, int rb, int cb,
                                 float& er, float& ei) {
    float a = 0.5f * (phi + om);
    float b = 0.5f * (phi - om);
    float cc = cosf(0.5f * th), ss = sinf(0.5f * th);
    if (rb == 0 && cb == 0) { er = cc * cosf(a); ei = -cc * sinf(a); }
    else if (rb == 0 && cb == 1) { er = -ss * cosf(b); ei = -ss * sinf(b); }
    else if (rb == 1 && cb == 0) { er = ss * cosf(b); ei = -ss * sinf(b); }
    else { er = cc * cosf(a); ei = cc * sinf(a); }
}

__device__ inline void layer_elem(const float* __restrict__ w, int l, int r,
                                  int c, float& pr, float& pi) {
    pr = 1.f; pi = 0.f;
    #pragma unroll
    for (int i = 0; i < WIRES; ++i) {
        const float* wi = w + (l * WIRES + i) * 3;
        float er, ei;
        int rb = (r >> (3 - i)) & 1, cb = (c >> (3 - i)) & 1;
        rot_entry(wi[0], wi[1], wi[2], rb, cb, er, ei);
        float nr = pr * er - pi * ei;
        float ni = pr * ei + pi * er;
        pr = nr; pi = ni;
    }
}

__device__ inline int cnot_src(int r, int range) {
    int src = r;
    #pragma unroll
    for (int i = WIRES - 1; i >= 0; --i) {
        int control = i, target = (i + range) & 3;
        int cbit = 1 << (3 - control), tbit = 1 << (3 - target);
        if (src & cbit) src ^= tbit;
    }
    return src;
}

__global__ __launch_bounds__(256) void build_unitary(
        const float* __restrict__ w, float* __restrict__ uout) {
    __shared__ float Lr[DIM][DIM], Li[DIM][DIM];
    __shared__ float Ur[DIM][DIM], Ui[DIM][DIM];
    __shared__ float Tr[DIM][DIM], Ti[DIM][DIM];
    int t = threadIdx.x;
    int r = t >> 4, c = t & 15;

    float lr, li;
    layer_elem(w, 0, r, c, lr, li);
    Lr[r][c] = lr; Li[r][c] = li;
    __syncthreads();
    int s0 = cnot_src(r, 1);                 // layer 0: range = 1
    Ur[r][c] = Lr[s0][c]; Ui[r][c] = Li[s0][c];
    __syncthreads();

    layer_elem(w, 1, r, c, lr, li);
    Lr[r][c] = lr; Li[r][c] = li;
    __syncthreads();
    float ar = 0.f, ai = 0.f;
    #pragma unroll
    for (int m = 0; m < DIM; ++m) {
        float xr = Lr[r][m], xi = Li[r][m];
        float yr = Ur[m][c], yi = Ui[m][c];
        ar += xr * yr - xi * yi;
        ai += xr * yi + xi * yr;
    }
    Tr[r][c] = ar; Ti[r][c] = ai;
    __syncthreads();
    int s1 = cnot_src(r, 2);                 // layer 1: range = 2
    uout[r * DIM + c]       = Tr[s1][c];
    uout[256 + r * DIM + c] = Ti[s1][c];
}

#define H 256
#define W 256
#define NB 32
#define OUTC 16
#define RPB 4            // output rows per block
#define LDSW 264         // row pitch: 264*4 B = 1056 B, 16 B-aligned rows

__global__ __launch_bounds__(256) void qconv_kernel(
        const float* __restrict__ x, const float* __restrict__ u,
        float* __restrict__ out) {
    __shared__ float sUr[OUTC][9];
    __shared__ float sUi[OUTC][9];
    __shared__ float rows[RPB + 2][LDSW];   // cols 0..257 map to j = c-1

    int t = threadIdx.x;
    int blk = blockIdx.x;            // 0 .. NB*(H/RPB)-1
    int b  = blk >> 6;               // image
    int i0 = (blk & 63) * RPB;       // first output row

    if (t < OUTC * 9) {
        int k = t / 9, m = t % 9;
        sUr[k][m] = u[k * DIM + m];
        sUi[k][m] = u[256 + k * DIM + m];
    }

    const float* xb = x + (size_t)b * H * W;
    #pragma unroll
    for (int r = 0; r < RPB + 2; ++r) {
        int gr = i0 + r - 1;
        for (int c = t; c < W + 2; c += 256) {
            int j = c - 1;
            float v = 0.01f;
            if ((unsigned)gr < (unsigned)H && (unsigned)j < (unsigned)W)
                v = xb[gr * W + j];
            rows[r][c] = v;
        }
    }
    __syncthreads();

    int lr = t >> 6;                 // wave index = local row 0..3
    int j0 = (t & 63) * 4;           // first of 4 pixels; 16 B-aligned LDS col

    float win[3][6];
    #pragma unroll
    for (int di = 0; di < 3; ++di) {
        float4 a  = *(const float4*)&rows[lr + di][j0];
        float2 bb = *(const float2*)&rows[lr + di][j0 + 4];
        win[di][0] = a.x;  win[di][1] = a.y;  win[di][2] = a.z;
        win[di][3] = a.w;  win[di][4] = bb.x; win[di][5] = bb.y;
    }

    float factor[4];
    #pragma unroll
    for (int q = 0; q < 4; ++q) {
        float n2 = 0.f;
        #pragma unroll
        for (int di = 0; di < 3; ++di)
            #pragma unroll
            for (int dj = 0; dj < 3; ++dj) {
                float v = win[di][q + dj];
                n2 = fmaf(v, v, n2);
            }
        // (DIM*0.5)/max(||p||,1e-12)^2 ; max(n,e)^2 == max(n^2,e^2), n>=0
        factor[q] = 8.0f / fmaxf(n2, 1e-24f);
    }

    int i = i0 + lr;
    float* ob = out + ((size_t)b * OUTC * H + i) * W + j0;

    #pragma unroll 4
    for (int k = 0; k < OUTC; ++k) {
        float cr[9], ci[9];
        #pragma unroll
        for (int m = 0; m < 9; ++m) { cr[m] = sUr[k][m]; ci[m] = sUi[k][m]; }
        float4 o;
        float* op = &o.x;
        #pragma unroll
        for (int q = 0; q < 4; ++q) {
            float sr = 0.f, si = 0.f;
            #pragma unroll
            for (int di = 0; di < 3; ++di)
                #pragma unroll
                for (int dj = 0; dj < 3; ++dj) {
                    float v = win[di][q + dj];
                    int m = di * 3 + dj;
                    sr = fmaf(cr[m], v, sr);
                    si = fmaf(ci[m], v, si);
                }
            op[q] = fminf(factor[q] * (sr * sr + si * si), 1.0f);
        }
        *(float4*)(ob + (size_t)k * H * W) = o;
    }
}

extern "C" void kernel_launch(void* const* d_in, const int* in_sizes, int n_in,
                              void* d_out, int out_size, void* d_ws, size_t ws_size,
                              hipStream_t stream) {
    const float* x = (const float*)d_in[0];        // (32,1,256,256) fp32
    const float* w = (const float*)d_in[1];        // (2,4,3) fp32
    float* out = (float*)d_out;                    // (32,16,256,256) fp32
    float* uws = (float*)d_ws;                     // 512 floats: Re | Im

    build_unitary<<<1, 256, 0, stream>>>(w, uws);
    qconv_kernel<<<NB * (H / RPB), 256, 0, stream>>>(x, uws, out);
}